// Round 1
// baseline (284.096 us; speedup 1.0000x reference)
//
#include <hip/hip_runtime.h>
#include <math.h>

#define NN 2048
#define BB 64
#define DD 512
#define NSEL 512  // NN/4

// ---------------------------------------------------------------------------
// Kernel 1: per-row 5th-largest value (thr) for attention (rows 0..63) and
// att_off (rows 64..127). One wave (64 lanes) per row.
// ---------------------------------------------------------------------------
__device__ __forceinline__ void insert5(float v, float t[5]) {
  if (v > t[4]) {
    if (v > t[0])      { t[4]=t[3]; t[3]=t[2]; t[2]=t[1]; t[1]=t[0]; t[0]=v; }
    else if (v > t[1]) { t[4]=t[3]; t[3]=t[2]; t[2]=t[1]; t[1]=v; }
    else if (v > t[2]) { t[4]=t[3]; t[3]=t[2]; t[2]=v; }
    else if (v > t[3]) { t[4]=t[3]; t[3]=v; }
    else               { t[4]=v; }
  }
}

__global__ void thr_kernel(const float* __restrict__ att,
                           const float* __restrict__ aoff,
                           float* __restrict__ thr) {
  int blk  = blockIdx.x;                 // 0..127
  const float* src = (blk < BB) ? att : aoff;
  int row  = (blk < BB) ? blk : blk - BB;
  int lane = threadIdx.x;                // 0..63

  float t[5] = {-INFINITY, -INFINITY, -INFINITY, -INFINITY, -INFINITY};
  const float* rp = src + (size_t)row * NN;
  #pragma unroll
  for (int k = 0; k < NN / 64; ++k) insert5(rp[lane + 64 * k], t);

  // Butterfly merge of sorted-descending 5-lists across the 64-lane wave.
  for (int off = 1; off < 64; off <<= 1) {
    float b[5];
    #pragma unroll
    for (int k = 0; k < 5; ++k) b[k] = __shfl_xor(t[k], off, 64);
    float m[5];
    int ia = 0, ib = 0;
    #pragma unroll
    for (int k = 0; k < 5; ++k) {
      float av = t[ia], bv = b[ib];
      bool ta = (av >= bv);
      m[k] = ta ? av : bv;
      ia += ta ? 1 : 0;
      ib += ta ? 0 : 1;
    }
    #pragma unroll
    for (int k = 0; k < 5; ++k) t[k] = m[k];
  }
  if (lane == 0) thr[blk] = t[4];        // 5th largest (vals[:, PS])
}

// ---------------------------------------------------------------------------
// Kernel 2: key[n] = sum_b (att[b,n] >= thr_att[b]) + sum_b (aoff[b,n] >= thr_off[b])
// key == 2*M, integer in [0,128]. Ordering by key == ordering by M.
// ---------------------------------------------------------------------------
__global__ void mkey_kernel(const float* __restrict__ att,
                            const float* __restrict__ aoff,
                            const float* __restrict__ thr,
                            int* __restrict__ key) {
  int n = blockIdx.x * blockDim.x + threadIdx.x;
  if (n >= NN) return;
  int c = 0;
  #pragma unroll 4
  for (int b = 0; b < BB; ++b) c += (att[(size_t)b * NN + n] >= thr[b]) ? 1 : 0;
  #pragma unroll 4
  for (int b = 0; b < BB; ++b) c += (aoff[(size_t)b * NN + n] >= thr[BB + b]) ? 1 : 0;
  key[n] = c;
}

// ---------------------------------------------------------------------------
// Kernel 3: stable descending counting-sort; emit top 512 indices.
// Matches jnp.argsort(-M) with stable=True: larger key first, ties by
// ascending index. Single block.
// ---------------------------------------------------------------------------
__global__ void topm_kernel(const int* __restrict__ key,
                            int* __restrict__ top_m,
                            float* __restrict__ out_tail) {
  __shared__ int kl[NN];
  __shared__ int hist[130];
  __shared__ int base[130];
  int t = threadIdx.x;
  for (int i = t; i < 130; i += blockDim.x) hist[i] = 0;
  __syncthreads();
  for (int i = t; i < NN; i += blockDim.x) {
    int k = key[i];
    kl[i] = k;
    atomicAdd(&hist[k], 1);
  }
  __syncthreads();
  if (t == 0) {
    int acc = 0;
    for (int k = 128; k >= 0; --k) { base[k] = acc; acc += hist[k]; }
  }
  __syncthreads();
  if (t < 129) {
    int r = base[t];
    if (r < NSEL) {
      for (int n = 0; n < NN; ++n) {
        if (kl[n] == t) {
          if (r < NSEL) {
            top_m[r] = n;
            out_tail[r] = (float)n;   // harness reads whole d_out as f32
          }
          ++r;
          if (r >= NSEL) break;
        }
      }
    }
  }
}

// ---------------------------------------------------------------------------
// Kernel 4: x_sel[b,i,:] = x[b, top_m[i], :]   (coalesced float4 copy, 2KB/row)
// grid = BB*NSEL blocks, 128 threads.
// ---------------------------------------------------------------------------
__global__ void xgather_kernel(const float* __restrict__ x,
                               const int* __restrict__ top_m,
                               float* __restrict__ xs) {
  int blk = blockIdx.x;
  int b = blk >> 9;             // / NSEL
  int i = blk & (NSEL - 1);
  int r = top_m[i];
  const float4* src = (const float4*)(x + ((size_t)b * NN + r) * DD);
  float4*       dst = (float4*)(xs + ((size_t)b * NSEL + i) * DD);
  dst[threadIdx.x] = src[threadIdx.x];
}

// ---------------------------------------------------------------------------
// Kernel 5: y_sel[b,i,j] = y[b, top_m[i], top_m[j]].
// Stage the full 8KB row in LDS (coalesced), gather 512 columns from LDS,
// write 2KB coalesced. grid = BB*NSEL blocks, 256 threads.
// ---------------------------------------------------------------------------
__global__ void ygather_kernel(const float* __restrict__ y,
                               const int* __restrict__ top_m,
                               float* __restrict__ ys) {
  __shared__ float row[NN];
  __shared__ int cols[NSEL];
  int blk = blockIdx.x;
  int b = blk >> 9;
  int i = blk & (NSEL - 1);
  int t = threadIdx.x;          // 0..255

  for (int j = t; j < NSEL; j += 256) cols[j] = top_m[j];
  int r = top_m[i];

  const float4* src = (const float4*)(y + (size_t)b * NN * NN + (size_t)r * NN);
  float4* row4 = (float4*)row;
  row4[t]       = src[t];
  row4[t + 256] = src[t + 256];
  __syncthreads();

  float* dst = ys + ((size_t)b * NSEL + i) * DD;
  dst[t]       = row[cols[t]];
  dst[t + 256] = row[cols[t + 256]];
}

// ---------------------------------------------------------------------------
extern "C" void kernel_launch(void* const* d_in, const int* in_sizes, int n_in,
                              void* d_out, int out_size, void* d_ws, size_t ws_size,
                              hipStream_t stream) {
  const float* x    = (const float*)d_in[0];   // (64, 2048, 512)
  const float* y    = (const float*)d_in[1];   // (64, 2048, 2048)
  const float* att  = (const float*)d_in[2];   // (64, 2048)
  const float* aoff = (const float*)d_in[3];   // (64, 2048)

  float* out = (float*)d_out;
  float* xs   = out;                                    // 64*512*512
  float* ysel = out + (size_t)BB * NSEL * DD;           // 64*512*512
  float* tail = ysel + (size_t)BB * NSEL * NSEL;        // 512 floats

  float* thr   = (float*)d_ws;                          // 128 floats
  int*   key   = (int*)d_ws + 128;                      // 2048 ints
  int*   top_m = (int*)d_ws + 128 + NN;                 // 512 ints

  hipLaunchKernelGGL(thr_kernel, dim3(2 * BB), dim3(64), 0, stream, att, aoff, thr);
  hipLaunchKernelGGL(mkey_kernel, dim3(NN / 256), dim3(256), 0, stream, att, aoff, thr, key);
  hipLaunchKernelGGL(topm_kernel, dim3(1), dim3(256), 0, stream, key, top_m, tail);
  hipLaunchKernelGGL(xgather_kernel, dim3(BB * NSEL), dim3(128), 0, stream, x, top_m, xs);
  hipLaunchKernelGGL(ygather_kernel, dim3(BB * NSEL), dim3(256), 0, stream, y, top_m, ysel);
}

// Round 2
// 130.077 us; speedup vs baseline: 2.1841x; 2.1841x over previous
//
#include <hip/hip_runtime.h>
#include <math.h>

#define NN 2048
#define BB 64
#define DD 512
#define NSEL 512  // NN/4

// ---------------------------------------------------------------------------
// Kernel 1: per-row 5th-largest value (thr) for attention (rows 0..63) and
// att_off (rows 64..127). One wave (64 lanes) per row.
// ---------------------------------------------------------------------------
__device__ __forceinline__ void insert5(float v, float t[5]) {
  if (v > t[4]) {
    if (v > t[0])      { t[4]=t[3]; t[3]=t[2]; t[2]=t[1]; t[1]=t[0]; t[0]=v; }
    else if (v > t[1]) { t[4]=t[3]; t[3]=t[2]; t[2]=t[1]; t[1]=v; }
    else if (v > t[2]) { t[4]=t[3]; t[3]=t[2]; t[2]=v; }
    else if (v > t[3]) { t[4]=t[3]; t[3]=v; }
    else               { t[4]=v; }
  }
}

__global__ void thr_kernel(const float* __restrict__ att,
                           const float* __restrict__ aoff,
                           float* __restrict__ thr) {
  int blk  = blockIdx.x;                 // 0..127
  const float* src = (blk < BB) ? att : aoff;
  int row  = (blk < BB) ? blk : blk - BB;
  int lane = threadIdx.x;                // 0..63

  float t[5] = {-INFINITY, -INFINITY, -INFINITY, -INFINITY, -INFINITY};
  const float* rp = src + (size_t)row * NN;
  #pragma unroll
  for (int k = 0; k < NN / 64; ++k) insert5(rp[lane + 64 * k], t);

  // Butterfly merge of sorted-descending 5-lists across the 64-lane wave.
  for (int off = 1; off < 64; off <<= 1) {
    float b[5];
    #pragma unroll
    for (int k = 0; k < 5; ++k) b[k] = __shfl_xor(t[k], off, 64);
    float m[5];
    int ia = 0, ib = 0;
    #pragma unroll
    for (int k = 0; k < 5; ++k) {
      float av = t[ia], bv = b[ib];
      bool ta = (av >= bv);
      m[k] = ta ? av : bv;
      ia += ta ? 1 : 0;
      ib += ta ? 0 : 1;
    }
    #pragma unroll
    for (int k = 0; k < 5; ++k) t[k] = m[k];
  }
  if (lane == 0) thr[blk] = t[4];        // 5th largest (vals[:, PS])
}

// ---------------------------------------------------------------------------
// Kernel 2: key[n] = #(att[:,n] >= thr_att) + #(aoff[:,n] >= thr_off) == 2*M.
// Integer in [0,128]; ordering by key == ordering by M (BETA=0.5 exact).
// ---------------------------------------------------------------------------
__global__ void mkey_kernel(const float* __restrict__ att,
                            const float* __restrict__ aoff,
                            const float* __restrict__ thr,
                            int* __restrict__ key) {
  int n = blockIdx.x * blockDim.x + threadIdx.x;
  if (n >= NN) return;
  int c = 0;
  #pragma unroll 16
  for (int b = 0; b < BB; ++b) c += (att[(size_t)b * NN + n] >= thr[b]) ? 1 : 0;
  #pragma unroll 16
  for (int b = 0; b < BB; ++b) c += (aoff[(size_t)b * NN + n] >= thr[BB + b]) ? 1 : 0;
  key[n] = c;
}

// ---------------------------------------------------------------------------
// Kernel 3: fully parallel stable descending counting-sort; emit top 512.
// rank(n) = #(key > k) + #(same key, earlier chunk) + #(same key, earlier in
// chunk). Matches jnp.argsort(-M) stable semantics exactly.
// One block, 1024 threads; element n handled by thread n (pass0) / n-1024
// (pass1); chunk = n>>6 (wave-aligned, so in-chunk order == lane order).
// ---------------------------------------------------------------------------
__global__ void __launch_bounds__(1024)
topm_kernel(const int* __restrict__ key,
            int* __restrict__ top_m,
            float* __restrict__ out_tail) {
  __shared__ int kl[NN];
  __shared__ int chist[32][132];   // [chunk][bucket], padded
  __shared__ int htot[132];
  __shared__ int gbase[132];
  int t = threadIdx.x;             // 0..1023

  for (int i = t; i < 32 * 132; i += 1024) (&chist[0][0])[i] = 0;
  __syncthreads();

  int k0 = key[t];
  int k1 = key[t + 1024];
  kl[t] = k0;
  kl[t + 1024] = k1;
  int c0 = t >> 6;
  int c1 = 16 + (t >> 6);
  atomicAdd(&chist[c0][k0], 1);
  atomicAdd(&chist[c1][k1], 1);
  __syncthreads();

  // Per-bucket: exclusive prefix over chunks; total count per bucket.
  if (t < 129) {
    int run = 0;
    #pragma unroll 4
    for (int c = 0; c < 32; ++c) { int v = chist[c][t]; chist[c][t] = run; run += v; }
    htot[t] = run;
  }
  __syncthreads();
  // gbase[k] = #elements with key > k (descending-stable base).
  if (t == 0) {
    int acc = 0;
    for (int k = 128; k >= 0; --k) { gbase[k] = acc; acc += htot[k]; }
  }
  __syncthreads();

  // In-chunk stable prefix: count same-key elements earlier in my chunk.
  int n0 = t, n1 = t + 1024;
  int pre0 = 0;
  for (int j = c0 * 64; j < n0; ++j) pre0 += (kl[j] == k0) ? 1 : 0;
  int pre1 = 0;
  for (int j = c1 * 64; j < n1; ++j) pre1 += (kl[j] == k1) ? 1 : 0;

  int r0 = gbase[k0] + chist[c0][k0] + pre0;
  int r1 = gbase[k1] + chist[c1][k1] + pre1;
  if (r0 < NSEL) { top_m[r0] = n0; out_tail[r0] = (float)n0; }
  if (r1 < NSEL) { top_m[r1] = n1; out_tail[r1] = (float)n1; }
}

// ---------------------------------------------------------------------------
// Kernel 4 (fused): per (b,i) block:
//   x_sel[b,i,:] = x[b,r,:]          (2KB float4 copy, threads 0..127)
//   y_sel[b,i,j] = y[b,r,top_m[j]]   (8KB row staged in LDS, 512-col gather)
// grid = BB*NSEL blocks, 256 threads. Both HBM streams overlap.
// ---------------------------------------------------------------------------
__global__ void gather_kernel(const float* __restrict__ x,
                              const float* __restrict__ y,
                              const int* __restrict__ top_m,
                              float* __restrict__ xs,
                              float* __restrict__ ys) {
  __shared__ float row[NN];
  __shared__ int cols[NSEL];
  int blk = blockIdx.x;
  int b = blk >> 9;
  int i = blk & (NSEL - 1);
  int t = threadIdx.x;          // 0..255

  int r = top_m[i];             // L2-hot broadcast load

  // y row -> LDS (coalesced float4, 4KB per instruction across the block)
  const float4* src = (const float4*)(y + (size_t)b * NN * NN + (size_t)r * NN);
  float4* row4 = (float4*)row;
  row4[t]       = src[t];
  row4[t + 256] = src[t + 256];

  for (int j = t; j < NSEL; j += 256) cols[j] = top_m[j];

  // x row copy (independent of LDS)
  if (t < 128) {
    const float4* xsrc = (const float4*)(x + ((size_t)b * NN + r) * DD);
    float4*       xdst = (float4*)(xs + ((size_t)b * NSEL + i) * DD);
    xdst[t] = xsrc[t];
  }
  __syncthreads();

  float* dst = ys + ((size_t)b * NSEL + i) * DD;
  dst[t]       = row[cols[t]];
  dst[t + 256] = row[cols[t + 256]];
}

// ---------------------------------------------------------------------------
extern "C" void kernel_launch(void* const* d_in, const int* in_sizes, int n_in,
                              void* d_out, int out_size, void* d_ws, size_t ws_size,
                              hipStream_t stream) {
  const float* x    = (const float*)d_in[0];   // (64, 2048, 512)
  const float* y    = (const float*)d_in[1];   // (64, 2048, 2048)
  const float* att  = (const float*)d_in[2];   // (64, 2048)
  const float* aoff = (const float*)d_in[3];   // (64, 2048)

  float* out = (float*)d_out;
  float* xs   = out;                                    // 64*512*512
  float* ysel = out + (size_t)BB * NSEL * DD;           // 64*512*512
  float* tail = ysel + (size_t)BB * NSEL * NSEL;        // 512 floats

  float* thr   = (float*)d_ws;                          // 128 floats
  int*   key   = (int*)d_ws + 128;                      // 2048 ints
  int*   top_m = (int*)d_ws + 128 + NN;                 // 512 ints

  hipLaunchKernelGGL(thr_kernel, dim3(2 * BB), dim3(64), 0, stream, att, aoff, thr);
  hipLaunchKernelGGL(mkey_kernel, dim3(NN / 256), dim3(256), 0, stream, att, aoff, thr, key);
  hipLaunchKernelGGL(topm_kernel, dim3(1), dim3(1024), 0, stream, key, top_m, tail);
  hipLaunchKernelGGL(gather_kernel, dim3(BB * NSEL), dim3(256), 0, stream, x, y, top_m, xs, ysel);
}